// Round 2
// baseline (43.006 us; speedup 1.0000x reference)
//
#include <hip/hip_runtime.h>
#include <math.h>

#define ALPHA 0.001f
#define BETA  0.001f
#define EPS   1e-32f

constexpr int BLOCK  = 256;
constexpr int JCHUNK = 2048;   // j-span per block (read via scalar loads, no LDS)

// Kernel 1: e[i] = log(dur[i]+EPS) - log_h[i]; per-block partials of e^2 and log_h^2.
__global__ void e_kernel(const float* __restrict__ log_h,
                         const float* __restrict__ dur,
                         float* __restrict__ e,
                         float* __restrict__ e2p,
                         float* __restrict__ lh2p,
                         int n) {
    int i = blockIdx.x * BLOCK + threadIdx.x;
    float e2 = 0.f, l2 = 0.f;
    if (i < n) {
        float lh = log_h[i];
        float ei = logf(dur[i] + EPS) - lh;
        e[i] = ei;
        e2 = ei * ei;
        l2 = lh * lh;
    }
    for (int off = 32; off; off >>= 1) {
        e2 += __shfl_down(e2, off);
        l2 += __shfl_down(l2, off);
    }
    __shared__ float we[BLOCK / 64], wl[BLOCK / 64];
    int tid = threadIdx.x;
    if ((tid & 63) == 0) { we[tid >> 6] = e2; wl[tid >> 6] = l2; }
    __syncthreads();
    if (tid == 0) {
        float te = 0.f, tl = 0.f;
        for (int w = 0; w < BLOCK / 64; ++w) { te += we[w]; tl += wl[w]; }
        e2p[blockIdx.x]  = te;
        lh2p[blockIdx.x] = tl;
    }
}

// Kernel 2: per (i-block, j-chunk), each thread owns one i and sweeps the chunk.
// Sum_j relu(e_j - e_i) = Sum_j max(e_j, e_i) - count * e_i   (2 VALU ops/pair).
// e_j addresses are wave-uniform -> compiler emits s_load (scalar pipe), no LDS.
__global__ __launch_bounds__(BLOCK) void pair_kernel(const float* __restrict__ e,
                                                     const float* __restrict__ events,
                                                     float* __restrict__ lossp,
                                                     int n) {
    const int tid = threadIdx.x;
    const int i   = blockIdx.x * BLOCK + tid;
    const int j0  = blockIdx.y * JCHUNK;
    const int jcount = min(JCHUNK, n - j0);

    const float ei = (i < n) ? e[i] : 0.f;
    const float ev = (i < n) ? events[i] : 0.f;
    const float* __restrict__ ej = e + j0;

    float acc[8] = {0.f, 0.f, 0.f, 0.f, 0.f, 0.f, 0.f, 0.f};
    const int kmain = jcount & ~7;
    #pragma unroll 4
    for (int k = 0; k < kmain; k += 8) {
        #pragma unroll
        for (int u = 0; u < 8; ++u)
            acc[u] += fmaxf(ej[k + u], ei);   // uniform addr -> s_load, v_max, v_add
    }
    float tail = 0.f;
    for (int k = kmain; k < jcount; ++k) tail += fmaxf(ej[k], ei);

    float s = ((acc[0] + acc[1]) + (acc[2] + acc[3]))
            + ((acc[4] + acc[5]) + (acc[6] + acc[7])) + tail;
    // T = sum(max) - count*ei ; weight by events[i]
    float sum = ev * (s - (float)jcount * ei);

    for (int off = 32; off; off >>= 1) sum += __shfl_down(sum, off);
    __shared__ float ws[BLOCK / 64];
    if ((tid & 63) == 0) ws[tid >> 6] = sum;
    __syncthreads();
    if (tid == 0) {
        float t = 0.f;
        for (int w = 0; w < BLOCK / 64; ++w) t += ws[w];
        lossp[blockIdx.y * gridDim.x + blockIdx.x] = t;
    }
}

// Kernel 3: combine partials with scaling.
__global__ void finalize_kernel(const float* __restrict__ lossp, int nloss,
                                const float* __restrict__ e2p,
                                const float* __restrict__ lh2p, int nb,
                                float* __restrict__ out, int n) {
    const int tid = threadIdx.x;
    const float invn  = 1.0f / (float)n;
    const float invn2 = invn * invn;
    float v = 0.f;
    for (int k = tid; k < nloss; k += BLOCK) v += lossp[k] * invn2;
    for (int k = tid; k < nb;    k += BLOCK) v += (ALPHA * e2p[k] + BETA * lh2p[k]) * invn;
    for (int off = 32; off; off >>= 1) v += __shfl_down(v, off);
    __shared__ float ws[BLOCK / 64];
    if ((tid & 63) == 0) ws[tid >> 6] = v;
    __syncthreads();
    if (tid == 0) {
        float t = 0.f;
        for (int w = 0; w < BLOCK / 64; ++w) t += ws[w];
        out[0] = t;
    }
}

extern "C" void kernel_launch(void* const* d_in, const int* in_sizes, int n_in,
                              void* d_out, int out_size, void* d_ws, size_t ws_size,
                              hipStream_t stream) {
    const float* log_h  = (const float*)d_in[0];
    const float* dur    = (const float*)d_in[1];
    const float* events = (const float*)d_in[2];
    float* out = (float*)d_out;
    const int n = in_sizes[1];            // 16384

    const int nib = (n + BLOCK  - 1) / BLOCK;    // 64 i-blocks
    const int njc = (n + JCHUNK - 1) / JCHUNK;   // 8 j-chunks

    float* e     = (float*)d_ws;          // n floats
    float* lossp = e + n;                 // nib*njc floats
    float* e2p   = lossp + nib * njc;     // nib floats
    float* lh2p  = e2p + nib;             // nib floats

    e_kernel<<<nib, BLOCK, 0, stream>>>(log_h, dur, e, e2p, lh2p, n);
    dim3 grid(nib, njc);
    pair_kernel<<<grid, BLOCK, 0, stream>>>(e, events, lossp, n);
    finalize_kernel<<<1, BLOCK, 0, stream>>>(lossp, nib * njc, e2p, lh2p, nib, out, n);
}

// Round 3
// 30.410 us; speedup vs baseline: 1.4142x; 1.4142x over previous
//
#include <hip/hip_runtime.h>
#include <math.h>

#define ALPHA 0.001f
#define BETA  0.001f
#define EPS   1e-32f

constexpr int BLOCK  = 256;
constexpr int ITILE  = 4;     // i-rows per thread (register tile)
constexpr int JCHUNK = 512;   // j-tile staged in LDS (2 KB)

// Kernel 1: e[i] = log(dur[i]+EPS) - log_h[i]; per-block partials of e^2 and log_h^2.
__global__ void e_kernel(const float* __restrict__ log_h,
                         const float* __restrict__ dur,
                         float* __restrict__ e,
                         float* __restrict__ e2p,
                         float* __restrict__ lh2p,
                         int n) {
    int i = blockIdx.x * BLOCK + threadIdx.x;
    float e2 = 0.f, l2 = 0.f;
    if (i < n) {
        float lh = log_h[i];
        float ei = logf(dur[i] + EPS) - lh;
        e[i] = ei;
        e2 = ei * ei;
        l2 = lh * lh;
    }
    for (int off = 32; off; off >>= 1) {
        e2 += __shfl_down(e2, off);
        l2 += __shfl_down(l2, off);
    }
    __shared__ float we[BLOCK / 64], wl[BLOCK / 64];
    int tid = threadIdx.x;
    if ((tid & 63) == 0) { we[tid >> 6] = e2; wl[tid >> 6] = l2; }
    __syncthreads();
    if (tid == 0) {
        float te = 0.f, tl = 0.f;
        for (int w = 0; w < BLOCK / 64; ++w) { te += we[w]; tl += wl[w]; }
        e2p[blockIdx.x]  = te;
        lh2p[blockIdx.x] = tl;
    }
}

// Kernel 2: per (i-superblock, j-chunk). Each thread owns ITILE i-rows; the
// j-chunk sits in LDS and every ds_read_b128 (broadcast) feeds 4*ITILE pairs.
// Sum_j relu(e_j - e_i) = Sum_j max(e_j, e_i) - jcount * e_i  (2 VALU ops/pair).
__global__ __launch_bounds__(BLOCK) void pair_kernel(const float* __restrict__ e,
                                                     const float* __restrict__ events,
                                                     float* __restrict__ lossp,
                                                     int n) {
    __shared__ float se[JCHUNK];
    const int tid = threadIdx.x;
    const int j0  = blockIdx.y * JCHUNK;
    const int jcount = min(JCHUNK, n - j0);

    if (tid * 4 < jcount)
        ((float4*)se)[tid] = ((const float4*)(e + j0))[tid];
    __syncthreads();

    const int i0 = blockIdx.x * (BLOCK * ITILE);
    float ei[ITILE], ev[ITILE], acc[ITILE];
    #pragma unroll
    for (int u = 0; u < ITILE; ++u) {
        int i = i0 + u * BLOCK + tid;
        ei[u]  = (i < n) ? e[i] : 0.f;
        ev[u]  = (i < n) ? events[i] : 0.f;
        acc[u] = 0.f;
    }

    const int k4 = jcount >> 2;
    #pragma unroll 2
    for (int k = 0; k < k4; ++k) {
        float4 v = ((const float4*)se)[k];   // uniform addr -> LDS broadcast
        #pragma unroll
        for (int u = 0; u < ITILE; ++u) {
            acc[u] += fmaxf(v.x, ei[u]);
            acc[u] += fmaxf(v.y, ei[u]);
            acc[u] += fmaxf(v.z, ei[u]);
            acc[u] += fmaxf(v.w, ei[u]);
        }
    }
    // (n is a multiple of 4; no scalar tail needed for jcount%4==0)

    float sum = 0.f;
    #pragma unroll
    for (int u = 0; u < ITILE; ++u)
        sum += ev[u] * (acc[u] - (float)jcount * ei[u]);

    for (int off = 32; off; off >>= 1) sum += __shfl_down(sum, off);
    __shared__ float ws[BLOCK / 64];
    if ((tid & 63) == 0) ws[tid >> 6] = sum;
    __syncthreads();
    if (tid == 0) {
        float t = 0.f;
        for (int w = 0; w < BLOCK / 64; ++w) t += ws[w];
        lossp[blockIdx.y * gridDim.x + blockIdx.x] = t;
    }
}

// Kernel 3: combine partials with scaling.
__global__ void finalize_kernel(const float* __restrict__ lossp, int nloss,
                                const float* __restrict__ e2p,
                                const float* __restrict__ lh2p, int nb,
                                float* __restrict__ out, int n) {
    const int tid = threadIdx.x;
    const float invn  = 1.0f / (float)n;
    const float invn2 = invn * invn;
    float v = 0.f;
    for (int k = tid; k < nloss; k += BLOCK) v += lossp[k] * invn2;
    for (int k = tid; k < nb;    k += BLOCK) v += (ALPHA * e2p[k] + BETA * lh2p[k]) * invn;
    for (int off = 32; off; off >>= 1) v += __shfl_down(v, off);
    __shared__ float ws[BLOCK / 64];
    if ((tid & 63) == 0) ws[tid >> 6] = v;
    __syncthreads();
    if (tid == 0) {
        float t = 0.f;
        for (int w = 0; w < BLOCK / 64; ++w) t += ws[w];
        out[0] = t;
    }
}

extern "C" void kernel_launch(void* const* d_in, const int* in_sizes, int n_in,
                              void* d_out, int out_size, void* d_ws, size_t ws_size,
                              hipStream_t stream) {
    const float* log_h  = (const float*)d_in[0];
    const float* dur    = (const float*)d_in[1];
    const float* events = (const float*)d_in[2];
    float* out = (float*)d_out;
    const int n = in_sizes[1];            // 16384

    const int neb = (n + BLOCK - 1) / BLOCK;               // 64 blocks for e_kernel
    const int nib = (n + BLOCK * ITILE - 1) / (BLOCK * ITILE);  // 16 i-superblocks
    const int njc = (n + JCHUNK - 1) / JCHUNK;             // 32 j-chunks

    float* e     = (float*)d_ws;          // n floats
    float* lossp = e + n;                 // nib*njc floats
    float* e2p   = lossp + nib * njc;     // neb floats
    float* lh2p  = e2p + neb;             // neb floats

    e_kernel<<<neb, BLOCK, 0, stream>>>(log_h, dur, e, e2p, lh2p, n);
    dim3 grid(nib, njc);
    pair_kernel<<<grid, BLOCK, 0, stream>>>(e, events, lossp, n);
    finalize_kernel<<<1, BLOCK, 0, stream>>>(lossp, nib * njc, e2p, lh2p, neb, out, n);
}

// Round 4
// 18.400 us; speedup vs baseline: 2.3373x; 1.6528x over previous
//
#include <hip/hip_runtime.h>
#include <math.h>

#define ALPHA 0.001f
#define BETA  0.001f
#define EPS   1e-32f

constexpr int BLOCK  = 256;
constexpr int ITILE  = 8;     // i-rows per thread (register tile)
constexpr int JCHUNK = 256;   // j-tile staged as f16 in LDS (512 B)

typedef _Float16 f16x2 __attribute__((ext_vector_type(2)));

// acc += a.x + a.y  via v_dot2_f32_f16(a, (1,1), acc)
__device__ __forceinline__ float dot2acc(f16x2 a, float c) {
#if __has_builtin(__builtin_amdgcn_fdot2)
    const f16x2 one2 = {(_Float16)1.0f, (_Float16)1.0f};
    return __builtin_amdgcn_fdot2(a, one2, c, false);
#else
    return c + (float)a.x + (float)a.y;
#endif
}

// Fused kernel: computes e inline (no precompute pass), then per (i-superblock,
// j-chunk) sums max(e_j, e_i) with pk_max_f16 + dot2 (1 VALU op per pair).
// Sum_j relu(e_j - e_i) = Sum_j max(e_j, e_i) - jcount * e_i.
// by==0 blocks also produce the quadratic-penalty partials for their i-range.
__global__ __launch_bounds__(BLOCK) void pair_fused_kernel(
        const float* __restrict__ log_h,
        const float* __restrict__ dur,
        const float* __restrict__ events,
        float* __restrict__ lossp,
        float* __restrict__ penp,
        int nib, int n) {
    __shared__ alignas(16) _Float16 se[JCHUNK];
    const int tid = threadIdx.x;
    const int bx = blockIdx.x, by = blockIdx.y;

    // stage j-chunk: e_j computed inline, stored f16 (JCHUNK == BLOCK, 1/thread)
    {
        int j = by * JCHUNK + tid;
        float ejf = logf(dur[j] + EPS) - log_h[j];
        se[tid] = (_Float16)ejf;
    }

    // i-rows (global loads overlap the staging; barrier comes after)
    const int i0 = bx * (BLOCK * ITILE);
    float acc[ITILE], ev[ITILE], eih[ITILE];
    float pen = 0.f;
    f16x2 ei2[ITILE];
    #pragma unroll
    for (int u = 0; u < ITILE; ++u) {
        int i = i0 + u * BLOCK + tid;
        float lh = log_h[i];
        float ei = logf(dur[i] + EPS) - lh;
        ev[u] = events[i];
        _Float16 h = (_Float16)ei;
        ei2[u] = (f16x2){h, h};
        eih[u] = (float)h;                    // rounded e_i: consistent with f16 max
        pen += ALPHA * ei * ei + BETA * lh * lh;
        acc[u] = 0.f;
    }
    __syncthreads();

    const uint4* sev = (const uint4*)se;      // 8 halves per ds_read_b128 (broadcast)
    #pragma unroll 4
    for (int k = 0; k < JCHUNK / 8; ++k) {
        uint4 raw = sev[k];
        f16x2 h0 = __builtin_bit_cast(f16x2, raw.x);
        f16x2 h1 = __builtin_bit_cast(f16x2, raw.y);
        f16x2 h2 = __builtin_bit_cast(f16x2, raw.z);
        f16x2 h3 = __builtin_bit_cast(f16x2, raw.w);
        #pragma unroll
        for (int u = 0; u < ITILE; ++u) {
            acc[u] = dot2acc(__builtin_elementwise_max(h0, ei2[u]), acc[u]);
            acc[u] = dot2acc(__builtin_elementwise_max(h1, ei2[u]), acc[u]);
            acc[u] = dot2acc(__builtin_elementwise_max(h2, ei2[u]), acc[u]);
            acc[u] = dot2acc(__builtin_elementwise_max(h3, ei2[u]), acc[u]);
        }
    }

    float loss = 0.f;
    #pragma unroll
    for (int u = 0; u < ITILE; ++u)
        loss += ev[u] * (acc[u] - (float)JCHUNK * eih[u]);

    // block reduce loss (and pen; pen only written by by==0)
    for (int off = 32; off; off >>= 1) {
        loss += __shfl_down(loss, off);
        pen  += __shfl_down(pen, off);
    }
    __shared__ float wl[BLOCK / 64], wp[BLOCK / 64];
    if ((tid & 63) == 0) { wl[tid >> 6] = loss; wp[tid >> 6] = pen; }
    __syncthreads();
    if (tid == 0) {
        float tl = 0.f, tp = 0.f;
        for (int w = 0; w < BLOCK / 64; ++w) { tl += wl[w]; tp += wp[w]; }
        lossp[by * nib + bx] = tl;
        if (by == 0) penp[bx] = tp;
    }
}

// Combine partials with scaling.
__global__ void finalize_kernel(const float* __restrict__ lossp, int nloss,
                                const float* __restrict__ penp, int npen,
                                float* __restrict__ out, int n) {
    const int tid = threadIdx.x;
    const float invn  = 1.0f / (float)n;
    const float invn2 = invn * invn;
    float v = 0.f;
    for (int k = tid; k < nloss; k += BLOCK) v += lossp[k] * invn2;
    for (int k = tid; k < npen;  k += BLOCK) v += penp[k] * invn;
    for (int off = 32; off; off >>= 1) v += __shfl_down(v, off);
    __shared__ float ws[BLOCK / 64];
    if ((tid & 63) == 0) ws[tid >> 6] = v;
    __syncthreads();
    if (tid == 0) {
        float t = 0.f;
        for (int w = 0; w < BLOCK / 64; ++w) t += ws[w];
        out[0] = t;
    }
}

extern "C" void kernel_launch(void* const* d_in, const int* in_sizes, int n_in,
                              void* d_out, int out_size, void* d_ws, size_t ws_size,
                              hipStream_t stream) {
    const float* log_h  = (const float*)d_in[0];
    const float* dur    = (const float*)d_in[1];
    const float* events = (const float*)d_in[2];
    float* out = (float*)d_out;
    const int n = in_sizes[1];                        // 16384

    const int nib = n / (BLOCK * ITILE);              // 8 i-superblocks
    const int njc = n / JCHUNK;                       // 64 j-chunks

    float* lossp = (float*)d_ws;                      // nib*njc floats
    float* penp  = lossp + nib * njc;                 // nib floats

    dim3 grid(nib, njc);
    pair_fused_kernel<<<grid, BLOCK, 0, stream>>>(log_h, dur, events,
                                                  lossp, penp, nib, n);
    finalize_kernel<<<1, BLOCK, 0, stream>>>(lossp, nib * njc, penp, nib, out, n);
}